// Round 11
// baseline (130.012 us; speedup 1.0000x reference)
//
#include <hip/hip_runtime.h>
#include <math.h>

// Problem constants
#define NVAL  97336           // 46^3 valid window positions
#define NCH   8               // N*C = 2*4 channels

typedef unsigned short u16;
typedef unsigned int u32;
typedef __attribute__((ext_vector_type(8))) short bf16x8;
typedef __attribute__((ext_vector_type(4))) float f32x4;
typedef __attribute__((ext_vector_type(4))) unsigned int u32x4;

// LDS staging geometry (gram kernel)
#define LINE_B 336            // 3 copies * 112 B per (x,y,vol) z-line
#define COPY_B 112            // 48 bf16 (96 B) + 16 B pad (bank spread)
#define VOL_B  21504          // 64 lines * 336
#define GLINE_U16 48          // global line: single copy, 48 u16 (96 B)

// ---------------------------------------------------------------------------
// Kernel 1: fused sigmoid/one-hot + 2x2x2 max-pool -> bf16, single copy per
// z-line. Each thread computes TWO pooled z-cells (float4/int4 loads).
// Also zeroes out[] (block 0), gacc (blocks 0..79), cnt (block 80).
// ---------------------------------------------------------------------------
__global__ __launch_bounds__(256) void pool_kernel(
    const float* __restrict__ logits, const int* __restrict__ labels,
    u16* __restrict__ shifted, float* __restrict__ gacc,
    int* __restrict__ cnt, float* __restrict__ out) {
  int t = blockIdx.x * 256 + threadIdx.x;
  if (t == 0) out[0] = 0.0f;
  if (blockIdx.x < 80) gacc[blockIdx.x * 256 + threadIdx.x] = 0.0f;
  if (blockIdx.x == 80 && threadIdx.x < NCH) cnt[threadIdx.x] = 0;
  // t -> (n, X, Y, Zp) ; Zp = pooled z pair index (covers pooled z 2Zp,2Zp+1)
  int Zp = t % 24; int tmp = t / 24;
  int Y = tmp % 48; tmp /= 48;
  int X = tmp % 48; int n = tmp / 48;
  int sb = (2 * X) * 9216 + (2 * Y) * 96 + 4 * Zp;   // raw base, 16B aligned
  const int4* lb4 = (const int4*)(labels + n * 884736 + sb);
  int4 La = lb4[0], Lb = lb4[24], Lc = lb4[2304], Ld = lb4[2328];
  #pragma unroll
  for (int c = 0; c < 4; c++) {
    const float4* lg4 = (const float4*)(logits + (size_t)(n * 4 + c) * 884736 + sb);
    float4 v0 = lg4[0], v1 = lg4[24], v2 = lg4[2304], v3 = lg4[2328];
    float mx0 = fmaxf(fmaxf(fmaxf(v0.x, v0.y), fmaxf(v1.x, v1.y)),
                      fmaxf(fmaxf(v2.x, v2.y), fmaxf(v3.x, v3.y)));
    float mx1 = fmaxf(fmaxf(fmaxf(v0.z, v0.w), fmaxf(v1.z, v1.w)),
                      fmaxf(fmaxf(v2.z, v2.w), fmaxf(v3.z, v3.w)));
    // max(sigmoid) == sigmoid(max); +1e-6 commutes with max
    float pr0 = 1.0f / (1.0f + expf(-mx0)) + 1e-6f;
    float pr1 = 1.0f / (1.0f + expf(-mx1)) + 1e-6f;
    int la0 = (La.x == c || La.y == c || Lb.x == c || Lb.y == c ||
               Lc.x == c || Lc.y == c || Ld.x == c || Ld.y == c);
    int la1 = (La.z == c || La.w == c || Lb.z == c || Lb.w == c ||
               Lc.z == c || Lc.w == c || Ld.z == c || Ld.w == c);
    u32 lapack = (la0 ? 0x3F80u : 0u) | (la1 ? 0x3F800000u : 0u);
    unsigned int q0 = __float_as_uint(pr0);        // round-to-nearest-even bf16
    unsigned int q1 = __float_as_uint(pr1);
    u32 p0 = (q0 + 0x7FFF + ((q0 >> 16) & 1)) >> 16;
    u32 p1 = (q1 + 0x7FFF + ((q1 >> 16) & 1)) & 0xFFFF0000u;
    u32 prpack = p0 | p1;
    int ch = n * 4 + c;
    int line = X * 48 + Y;
    ((u32*)shifted)[((size_t)(ch * 2 + 0) * 2304 + line) * 24 + Zp] = lapack;
    ((u32*)shifted)[((size_t)(ch * 2 + 1) * 2304 + line) * 24 + Zp] = prpack;
  }
}

// ---------------------------------------------------------------------------
// Kernel 2: Gram via MFMA + fused stage-2. W rows 0-26 = la shifts, 27-53 =
// pr shifts, 54 = ones (row sums), 55-63 = zero. G = (mask.W) W^T, upper
// triangle as 10 16x16 tiles, fp32-atomicAdd'ed into per-channel global Gram.
// The LAST block of each channel (completion counter) re-reads the Gram via
// device-scope atomics and runs the bordered 54x54 rank-8 elimination inline.
// ---------------------------------------------------------------------------
#define MFMA16(A, B, C) __builtin_amdgcn_mfma_f32_16x16x32_bf16((A), (B), (C), 0, 0, 0)

#define STEP(BA, AM) do {                                                  \
    int _ba = (BA);                                                        \
    u32x4 ub0 = *(const u32x4*)(smem + _ba + laneC0);                      \
    u32x4 ub1 = *(const u32x4*)(smem + _ba + laneC1);                      \
    u32x4 ub2 = *(const u32x4*)(smem + _ba + laneC2);                      \
    u32x4 ub3 = *(const u32x4*)(smem + _ba + laneC3);                      \
    ub3 = iszero ? zer4 : (isones ? one4 : ub3);                           \
    u32x4 ua0 = ub0, ua1 = ub1, ua2 = ub2, ua3 = ub3;                      \
    ua0.w &= (AM); ua1.w &= (AM); ua2.w &= (AM); ua3.w &= (AM);            \
    bf16x8 A0 = __builtin_bit_cast(bf16x8, ua0);                           \
    bf16x8 A1 = __builtin_bit_cast(bf16x8, ua1);                           \
    bf16x8 A2 = __builtin_bit_cast(bf16x8, ua2);                           \
    bf16x8 A3 = __builtin_bit_cast(bf16x8, ua3);                           \
    bf16x8 B0 = __builtin_bit_cast(bf16x8, ub0);                           \
    bf16x8 B1 = __builtin_bit_cast(bf16x8, ub1);                           \
    bf16x8 B2 = __builtin_bit_cast(bf16x8, ub2);                           \
    bf16x8 B3 = __builtin_bit_cast(bf16x8, ub3);                           \
    acc0 = MFMA16(A0, B0, acc0);  acc1 = MFMA16(A0, B1, acc1);             \
    acc2 = MFMA16(A0, B2, acc2);  acc3 = MFMA16(A0, B3, acc3);             \
    acc4 = MFMA16(A1, B1, acc4);  acc5 = MFMA16(A1, B2, acc5);             \
    acc6 = MFMA16(A1, B3, acc6);  acc7 = MFMA16(A2, B2, acc7);             \
    acc8 = MFMA16(A2, B3, acc8);  acc9 = MFMA16(A3, B3, acc9);             \
  } while (0)

#define MS 56   // elimination row stride (doubles), even for 16-B alignment

__device__ inline double g54(const float* __restrict__ G, int R, int C) {
  int I = R >> 4, J = C >> 4;
  if (I > J) { int tt = R; R = C; C = tt; I = R >> 4; J = C >> 4; }
  int tile = 4 * I - ((I * (I - 1)) >> 1) + (J - I);
  int r = R & 15, c = C & 15;
  return (double)G[tile * 256 + (r & 3) * 64 + ((r >> 2) << 4) + c];
}

__device__ inline int tri_row(int u) {
  int a = (int)((sqrtf(8.0f * (float)u + 1.0f) - 1.0f) * 0.5f);
  while ((a + 1) * (a + 2) / 2 <= u) a++;
  while (a * (a + 1) / 2 > u) a--;
  return a;
}

__global__ __launch_bounds__(256) void gram_kernel(
    const u16* __restrict__ shifted, float* __restrict__ gacc,
    int* __restrict__ cnt, float* __restrict__ out) {
  __shared__ __align__(16) unsigned char smem[43008];
  __shared__ int winflag;
  int bx = blockIdx.x;
  int ch = bx >> 6, xt = (bx >> 3) & 7, yt = bx & 7;
  int X0 = xt * 6, Y0 = yt * 6;
  int tw = (xt == 7) ? 4 : 6, th = (yt == 7) ? 4 : 6;
  int tid = threadIdx.x;

  // Stage fixed 8x8 lines x 2 vols; build 3 shifted copies in-register.
  const u16* base = shifted + (size_t)ch * 2 * 2304 * GLINE_U16;
  for (int j = tid; j < 768; j += 256) {         // 128 lines * 6 chunks
    int chunk = j % 6; int li = j / 6;           // li 0..127
    int sy = li & 7, sx = (li >> 3) & 7, vol = li >> 6;
    int gx = X0 + sx; if (gx > 47) gx = 47;      // clamp: garbage, never read
    int gy = Y0 + sy; if (gy > 47) gy = 47;
    const u32* src = (const u32*)(base +
        ((size_t)vol * 2304 + gx * 48 + gy) * GLINE_U16);
    u32x4 v = *(const u32x4*)(src + chunk * 4);
    u32 d4 = (chunk < 5) ? src[chunk * 4 + 4] : 0u;   // next dword; 0 at tail
    unsigned char* dstp = smem + vol * VOL_B + ((sx << 3) + sy) * LINE_B + chunk * 16;
    *(u32x4*)(dstp) = v;                                       // copy dz=0
    u32x4 s1 = { (v.x >> 16) | (v.y << 16), (v.y >> 16) | (v.z << 16),
                 (v.z >> 16) | (v.w << 16), (v.w >> 16) | (d4 << 16) };
    *(u32x4*)(dstp + COPY_B) = s1;                             // copy dz=1
    u32x4 s2 = { v.y, v.z, v.w, d4 };
    *(u32x4*)(dstp + 2 * COPY_B) = s2;                         // copy dz=2
  }
  __syncthreads();

  int lane = tid & 63, w = tid >> 6;
  int q = lane >> 4, rlo = lane & 15;
#define LANEC(F) ({ int _r = (F) * 16 + rlo; int _vol = 0, _s = 0;           \
    if (_r < 27) { _s = _r; } else if (_r < 54) { _vol = 1; _s = _r - 27; }  \
    int _dx = _s / 9, _dy = (_s / 3) % 3, _dz = _s % 3;                      \
    _vol * VOL_B + ((_dx << 3) + _dy) * LINE_B + _dz * COPY_B; })
  int laneC0 = LANEC(0), laneC1 = LANEC(1), laneC2 = LANEC(2), laneC3 = LANEC(3);
  unsigned int am1 = (q == 1) ? 0u : ~0u;
  unsigned int am2 = (q == 3) ? 0u : ~0u;
  bool isones = (rlo == 6);    // frag3 row 54 = ones
  bool iszero = (rlo > 6);     // frag3 rows 55-63 = zero
  u32x4 one4 = {0x3F803F80u, 0x3F803F80u, 0x3F803F80u, 0x3F803F80u};
  u32x4 zer4 = {0u, 0u, 0u, 0u};

  f32x4 acc0 = {0,0,0,0}, acc1 = {0,0,0,0}, acc2 = {0,0,0,0}, acc3 = {0,0,0,0};
  f32x4 acc4 = {0,0,0,0}, acc5 = {0,0,0,0}, acc6 = {0,0,0,0}, acc7 = {0,0,0,0};
  f32x4 acc8 = {0,0,0,0}, acc9 = {0,0,0,0};

  int npl = (tw * th) >> 1;
  for (int pl = w; pl < npl; pl += 4) {
    int L0 = 2 * pl, L1 = L0 + 1;
    int lx0 = L0 / th, ly0 = L0 - lx0 * th;
    int lx1 = L1 / th, ly1 = L1 - lx1 * th;
    int U0 = ((lx0 << 3) + ly0) * LINE_B;
    int U1 = ((lx1 << 3) + ly1) * LINE_B;
    STEP(U0 + 16 * q, ~0u);
    STEP((q < 2) ? (U0 + 64 + 16 * q) : (U1 + 16 * q - 32), am1);
    STEP(U1 + 32 + 16 * q, am2);
  }
  __syncthreads();

  float* Pf = (float*)smem;
#define FL(T, A) { float* _qp = Pf + w * 2560 + (T) * 256 + lane;            \
    _qp[0] = (A).x; _qp[64] = (A).y; _qp[128] = (A).z; _qp[192] = (A).w; }
  FL(0, acc0) FL(1, acc1) FL(2, acc2) FL(3, acc3) FL(4, acc4)
  FL(5, acc5) FL(6, acc6) FL(7, acc7) FL(8, acc8) FL(9, acc9)
  __syncthreads();
  float* dst = gacc + (size_t)ch * 2560;
  for (int u2 = tid; u2 < 2560; u2 += 256)
    atomicAdd(&dst[u2], Pf[u2] + Pf[u2 + 2560] + Pf[u2 + 5120] + Pf[u2 + 7680]);

  // ---- completion counter: last block of this channel runs stage-2 ----
  __threadfence();
  if (tid == 0) winflag = (atomicAdd(&cnt[ch], 1) == 63) ? 1 : 0;
  __syncthreads();
  if (!winflag) return;
  __threadfence();

  // LDS reuse: M (24192 B) | gsf fp32 Gram (10240 B) | slv/spv/piv/lred
  double* M = (double*)smem;
  float* gsf = (float*)(smem + 24192);
  double* slv = (double*)(smem + 34432);
  double* spv = (double*)(smem + 34648);
  double* piv = (double*)(smem + 34864);
  double* lred = (double*)(smem + 35296);
  const double Minv = 1.0 / (double)NVAL;
  const double alpha = 5e-4;

  // Device-coherent re-read of the completed Gram (atomic add-zero)
  for (int u2 = tid; u2 < 2560; u2 += 256)
    gsf[u2] = atomicAdd(&dst[u2], 0.0f);
  __syncthreads();
  const float* G = gsf;

  if (tid < 27) { slv[tid] = g54(G, tid, 54); spv[tid] = g54(G, 27 + tid, 54); }
  __syncthreads();
  // Build lower triangle of bordered matrix: 0..26 = pr dims, 27..53 = la
  for (int u = tid; u < 1485; u += 256) {
    int a = tri_row(u);
    int b = u - a * (a + 1) / 2;               // b <= a
    double v;
    if (a < 27) {                               // pr-pr
      v = g54(G, 27 + a, 27 + b) - spv[a] * spv[b] * Minv + ((a == b) ? alpha : 0.0);
    } else if (b >= 27) {                       // la-la
      int d = a - 27, e = b - 27;
      v = g54(G, d, e) - slv[d] * slv[e] * Minv + ((d == e) ? alpha : 0.0);
    } else {                                    // la row, pr col
      v = g54(G, a - 27, 27 + b) - slv[a - 27] * spv[b] * Minv;
    }
    M[a * MS + b] = v;
  }
  __syncthreads();

  #pragma unroll 1
  for (int phase = 0; phase < 6; phase++) {
    int k0 = phase * 8;
    // Load lower 8x8 pivot block (broadcast reads), factor LDL^T in regs
    double P[8][8];
    #pragma unroll
    for (int k = 0; k < 8; k++)
      #pragma unroll
      for (int j = 0; j <= k; j++)
        P[k][j] = M[(k0 + k) * MS + (k0 + j)];
    double idv[8];
    #pragma unroll
    for (int k = 0; k < 8; k++) {
      idv[k] = 1.0 / P[k][k];
      #pragma unroll
      for (int i = k + 1; i < 8; i++) {
        double l = P[i][k] * idv[k];
        #pragma unroll
        for (int j = k + 1; j <= i; j++)
          P[i][j] -= l * P[j][k];
      }
      #pragma unroll
      for (int i = k + 1; i < 8; i++) P[i][k] *= idv[k];
    }
    if (tid == 0) {
      #pragma unroll
      for (int k = 0; k < 8; k++) piv[k0 + k] = P[k][k];
    }
    int bstart = k0 + 8, n = 54 - bstart;
    int ncell = n * (n + 1) / 2;
    for (int u = tid; u < ncell; u += 256) {
      int ii = tri_row(u);
      int jj = u - ii * (ii + 1) / 2;
      int i = bstart + ii, j = bstart + jj;
      // 16-B aligned vector loads of the 8-double borders
      const double2* Ai = (const double2*)(M + i * MS + k0);
      const double2* Bj = (const double2*)(M + j * MS + k0);
      double2 a01 = Ai[0], a23 = Ai[1], a45 = Ai[2], a67 = Ai[3];
      double2 b01 = Bj[0], b23 = Bj[1], b45 = Bj[2], b67 = Bj[3];
      double av[8] = {a01.x, a01.y, a23.x, a23.y, a45.x, a45.y, a67.x, a67.y};
      double bv[8] = {b01.x, b01.y, b23.x, b23.y, b45.x, b45.y, b67.x, b67.y};
      #pragma unroll
      for (int k = 1; k < 8; k++) {
        #pragma unroll
        for (int m = 0; m < k; m++) {
          av[k] -= P[k][m] * av[m];
          bv[k] -= P[k][m] * bv[m];
        }
      }
      double acc = 0.0;
      #pragma unroll
      for (int k = 0; k < 8; k++) acc += av[k] * (bv[k] * idv[k]);
      M[i * MS + j] -= acc;
    }
    __syncthreads();
  }

  // Tail: 6x6 trailing block, pivots 48..53
  if (tid == 0) {
    double T[6][6];
    #pragma unroll
    for (int k = 0; k < 6; k++)
      #pragma unroll
      for (int j = 0; j <= k; j++)
        T[k][j] = M[(48 + k) * MS + (48 + j)];
    #pragma unroll
    for (int k = 0; k < 6; k++) {
      double dk = T[k][k];
      piv[48 + k] = dk;
      double id = 1.0 / dk;
      #pragma unroll
      for (int i = k + 1; i < 6; i++) {
        double l = T[i][k] * id;
        #pragma unroll
        for (int j = k + 1; j <= i; j++)
          T[i][j] -= l * T[j][k];
      }
    }
  }
  __syncthreads();

  if (tid < 27) lred[tid] = log(sqrt(piv[27 + tid]) + 1e-8);
  __syncthreads();
  if (tid == 0) {
    double s = 0.0;
    for (int i = 0; i < 27; i++) s += lred[i];
    atomicAdd(out, (float)(s / 54.0));
  }
}

// ---------------------------------------------------------------------------
extern "C" void kernel_launch(void* const* d_in, const int* in_sizes, int n_in,
                              void* d_out, int out_size, void* d_ws, size_t ws_size,
                              hipStream_t stream) {
  const float* logits = (const float*)d_in[0];
  const int* labels = (const int*)d_in[1];
  float* out = (float*)d_out;

  // ws layout: gacc fp32 (80 KB) | cnt (8 int) | shifted bf16 (3.6 MB)
  float* gacc = (float*)d_ws;
  int* cnt = (int*)((char*)d_ws + 81920);
  u16* shifted = (u16*)((char*)d_ws + 131072);

  pool_kernel<<<432, 256, 0, stream>>>(logits, labels, shifted, gacc, cnt, out);
  gram_kernel<<<512, 256, 0, stream>>>(shifted, gacc, cnt, out);
}

// Round 12
// 110.119 us; speedup vs baseline: 1.1806x; 1.1806x over previous
//
#include <hip/hip_runtime.h>
#include <math.h>

// Problem constants
#define NVAL  97336           // 46^3 valid window positions
#define NCH   8               // N*C = 2*4 channels
#define NREP  8               // Gram accumulator replicas (atomic decorrelation)
#define GSZ   20480           // NCH * 2560 floats per replica

typedef unsigned short u16;
typedef unsigned int u32;
typedef __attribute__((ext_vector_type(8))) short bf16x8;
typedef __attribute__((ext_vector_type(4))) float f32x4;
typedef __attribute__((ext_vector_type(4))) unsigned int u32x4;

// LDS staging geometry (gram kernel)
#define LINE_B 336            // 3 copies * 112 B per (x,y,vol) z-line
#define COPY_B 112            // 48 bf16 (96 B) + 16 B pad (bank spread)
#define VOL_B  21504          // 64 lines * 336
#define GLINE_U16 48          // global line: single copy, 48 u16 (96 B)

// ---------------------------------------------------------------------------
// Kernel 1: fused sigmoid/one-hot + 2x2x2 max-pool -> bf16, single copy per
// z-line. Each thread computes TWO pooled z-cells (float4/int4 loads).
// Also zeroes out[] and all Gram replicas (grid-stride).
// ---------------------------------------------------------------------------
__global__ __launch_bounds__(256) void pool_kernel(
    const float* __restrict__ logits, const int* __restrict__ labels,
    u16* __restrict__ shifted, float* __restrict__ gacc,
    float* __restrict__ out) {
  int t = blockIdx.x * 256 + threadIdx.x;
  if (t == 0) out[0] = 0.0f;
  for (int z = t; z < NREP * GSZ; z += 432 * 256) gacc[z] = 0.0f;
  // t -> (n, X, Y, Zp) ; Zp = pooled z pair index (covers pooled z 2Zp,2Zp+1)
  int Zp = t % 24; int tmp = t / 24;
  int Y = tmp % 48; tmp /= 48;
  int X = tmp % 48; int n = tmp / 48;
  int sb = (2 * X) * 9216 + (2 * Y) * 96 + 4 * Zp;   // raw base, 16B aligned
  const int4* lb4 = (const int4*)(labels + n * 884736 + sb);
  int4 La = lb4[0], Lb = lb4[24], Lc = lb4[2304], Ld = lb4[2328];
  #pragma unroll
  for (int c = 0; c < 4; c++) {
    const float4* lg4 = (const float4*)(logits + (size_t)(n * 4 + c) * 884736 + sb);
    float4 v0 = lg4[0], v1 = lg4[24], v2 = lg4[2304], v3 = lg4[2328];
    float mx0 = fmaxf(fmaxf(fmaxf(v0.x, v0.y), fmaxf(v1.x, v1.y)),
                      fmaxf(fmaxf(v2.x, v2.y), fmaxf(v3.x, v3.y)));
    float mx1 = fmaxf(fmaxf(fmaxf(v0.z, v0.w), fmaxf(v1.z, v1.w)),
                      fmaxf(fmaxf(v2.z, v2.w), fmaxf(v3.z, v3.w)));
    // max(sigmoid) == sigmoid(max); +1e-6 commutes with max
    float pr0 = 1.0f / (1.0f + expf(-mx0)) + 1e-6f;
    float pr1 = 1.0f / (1.0f + expf(-mx1)) + 1e-6f;
    int la0 = (La.x == c || La.y == c || Lb.x == c || Lb.y == c ||
               Lc.x == c || Lc.y == c || Ld.x == c || Ld.y == c);
    int la1 = (La.z == c || La.w == c || Lb.z == c || Lb.w == c ||
               Lc.z == c || Lc.w == c || Ld.z == c || Ld.w == c);
    u32 lapack = (la0 ? 0x3F80u : 0u) | (la1 ? 0x3F800000u : 0u);
    unsigned int q0 = __float_as_uint(pr0);        // round-to-nearest-even bf16
    unsigned int q1 = __float_as_uint(pr1);
    u32 p0 = (q0 + 0x7FFF + ((q0 >> 16) & 1)) >> 16;
    u32 p1 = (q1 + 0x7FFF + ((q1 >> 16) & 1)) & 0xFFFF0000u;
    u32 prpack = p0 | p1;
    int ch = n * 4 + c;
    int line = X * 48 + Y;
    ((u32*)shifted)[((size_t)(ch * 2 + 0) * 2304 + line) * 24 + Zp] = lapack;
    ((u32*)shifted)[((size_t)(ch * 2 + 1) * 2304 + line) * 24 + Zp] = prpack;
  }
}

// ---------------------------------------------------------------------------
// Kernel 2: Gram via MFMA. W rows 0-26 = la shifts, 27-53 = pr shifts,
// 54 = ones (row sums), 55-63 = zero. G = (mask.W) W^T, upper triangle as
// 10 16x16 tiles. Block = (ch, 6x6 xy-tile, K-half). The 3 z-shifted copies
// are built IN-REGISTER during staging (funnel shifts). Partials flushed
// with fp32 atomics into replica bx&7 (16-way max same-address contention).
// ---------------------------------------------------------------------------
#define MFMA16(A, B, C) __builtin_amdgcn_mfma_f32_16x16x32_bf16((A), (B), (C), 0, 0, 0)

#define STEP(BA, AM) do {                                                  \
    int _ba = (BA);                                                        \
    u32x4 ub0 = *(const u32x4*)(smem + _ba + laneC0);                      \
    u32x4 ub1 = *(const u32x4*)(smem + _ba + laneC1);                      \
    u32x4 ub2 = *(const u32x4*)(smem + _ba + laneC2);                      \
    u32x4 ub3 = *(const u32x4*)(smem + _ba + laneC3);                      \
    ub3 = iszero ? zer4 : (isones ? one4 : ub3);                           \
    u32x4 ua0 = ub0, ua1 = ub1, ua2 = ub2, ua3 = ub3;                      \
    ua0.w &= (AM); ua1.w &= (AM); ua2.w &= (AM); ua3.w &= (AM);            \
    bf16x8 A0 = __builtin_bit_cast(bf16x8, ua0);                           \
    bf16x8 A1 = __builtin_bit_cast(bf16x8, ua1);                           \
    bf16x8 A2 = __builtin_bit_cast(bf16x8, ua2);                           \
    bf16x8 A3 = __builtin_bit_cast(bf16x8, ua3);                           \
    bf16x8 B0 = __builtin_bit_cast(bf16x8, ub0);                           \
    bf16x8 B1 = __builtin_bit_cast(bf16x8, ub1);                           \
    bf16x8 B2 = __builtin_bit_cast(bf16x8, ub2);                           \
    bf16x8 B3 = __builtin_bit_cast(bf16x8, ub3);                           \
    acc0 = MFMA16(A0, B0, acc0);  acc1 = MFMA16(A0, B1, acc1);             \
    acc2 = MFMA16(A0, B2, acc2);  acc3 = MFMA16(A0, B3, acc3);             \
    acc4 = MFMA16(A1, B1, acc4);  acc5 = MFMA16(A1, B2, acc5);             \
    acc6 = MFMA16(A1, B3, acc6);  acc7 = MFMA16(A2, B2, acc7);             \
    acc8 = MFMA16(A2, B3, acc8);  acc9 = MFMA16(A3, B3, acc9);             \
  } while (0)

__global__ __launch_bounds__(256) void gram_kernel(
    const u16* __restrict__ shifted, float* __restrict__ gacc) {
  __shared__ __align__(16) unsigned char smem[43008];
  int bx = blockIdx.x;
  int half = bx & 1;
  int tile = (bx >> 1) & 63;
  int ch = bx >> 7;
  int xt = tile >> 3, yt = tile & 7;
  int X0 = xt * 6, Y0 = yt * 6;
  int tw = (xt == 7) ? 4 : 6, th = (yt == 7) ? 4 : 6;
  int tid = threadIdx.x;

  // Stage fixed 8x8 lines x 2 vols; build 3 shifted copies in-register.
  const u16* base = shifted + (size_t)ch * 2 * 2304 * GLINE_U16;
  for (int j = tid; j < 768; j += 256) {         // 128 lines * 6 chunks
    int chunk = j % 6; int li = j / 6;           // li 0..127
    int sy = li & 7, sx = (li >> 3) & 7, vol = li >> 6;
    int gx = X0 + sx; if (gx > 47) gx = 47;      // clamp: garbage, never read
    int gy = Y0 + sy; if (gy > 47) gy = 47;
    const u32* src = (const u32*)(base +
        ((size_t)vol * 2304 + gx * 48 + gy) * GLINE_U16);
    u32x4 v = *(const u32x4*)(src + chunk * 4);
    u32 d4 = (chunk < 5) ? src[chunk * 4 + 4] : 0u;   // next dword; 0 at tail
    unsigned char* dstp = smem + vol * VOL_B + ((sx << 3) + sy) * LINE_B + chunk * 16;
    *(u32x4*)(dstp) = v;                                       // copy dz=0
    u32x4 s1 = { (v.x >> 16) | (v.y << 16), (v.y >> 16) | (v.z << 16),
                 (v.z >> 16) | (v.w << 16), (v.w >> 16) | (d4 << 16) };
    *(u32x4*)(dstp + COPY_B) = s1;                             // copy dz=1
    u32x4 s2 = { v.y, v.z, v.w, d4 };
    *(u32x4*)(dstp + 2 * COPY_B) = s2;                         // copy dz=2
  }
  __syncthreads();

  int lane = tid & 63, w = tid >> 6;
  int q = lane >> 4, rlo = lane & 15;
#define LANEC(F) ({ int _r = (F) * 16 + rlo; int _vol = 0, _s = 0;           \
    if (_r < 27) { _s = _r; } else if (_r < 54) { _vol = 1; _s = _r - 27; }  \
    int _dx = _s / 9, _dy = (_s / 3) % 3, _dz = _s % 3;                      \
    _vol * VOL_B + ((_dx << 3) + _dy) * LINE_B + _dz * COPY_B; })
  int laneC0 = LANEC(0), laneC1 = LANEC(1), laneC2 = LANEC(2), laneC3 = LANEC(3);
  unsigned int am1 = (q == 1) ? 0u : ~0u;
  unsigned int am2 = (q == 3) ? 0u : ~0u;
  bool isones = (rlo == 6);    // frag3 row 54 = ones
  bool iszero = (rlo > 6);     // frag3 rows 55-63 = zero
  u32x4 one4 = {0x3F803F80u, 0x3F803F80u, 0x3F803F80u, 0x3F803F80u};
  u32x4 zer4 = {0u, 0u, 0u, 0u};

  f32x4 acc0 = {0,0,0,0}, acc1 = {0,0,0,0}, acc2 = {0,0,0,0}, acc3 = {0,0,0,0};
  f32x4 acc4 = {0,0,0,0}, acc5 = {0,0,0,0}, acc6 = {0,0,0,0}, acc7 = {0,0,0,0};
  f32x4 acc8 = {0,0,0,0}, acc9 = {0,0,0,0};

  // K-split: half h covers pl in [h*npl2, (h+1)*npl2); npl is always even
  int npl2 = (tw * th) >> 2;
  for (int pl = half * npl2 + w; pl < (half + 1) * npl2; pl += 4) {
    int L0 = 2 * pl, L1 = L0 + 1;
    int lx0 = L0 / th, ly0 = L0 - lx0 * th;
    int lx1 = L1 / th, ly1 = L1 - lx1 * th;
    int U0 = ((lx0 << 3) + ly0) * LINE_B;
    int U1 = ((lx1 << 3) + ly1) * LINE_B;
    STEP(U0 + 16 * q, ~0u);
    STEP((q < 2) ? (U0 + 64 + 16 * q) : (U1 + 16 * q - 32), am1);
    STEP(U1 + 32 + 16 * q, am2);
  }
  __syncthreads();

  float* Pf = (float*)smem;
#define FL(T, A) { float* _qp = Pf + w * 2560 + (T) * 256 + lane;            \
    _qp[0] = (A).x; _qp[64] = (A).y; _qp[128] = (A).z; _qp[192] = (A).w; }
  FL(0, acc0) FL(1, acc1) FL(2, acc2) FL(3, acc3) FL(4, acc4)
  FL(5, acc5) FL(6, acc6) FL(7, acc7) FL(8, acc8) FL(9, acc9)
  __syncthreads();
  float* dst = gacc + (bx & 7) * GSZ + ch * 2560;
  for (int u2 = tid; u2 < 2560; u2 += 256)
    atomicAdd(&dst[u2], Pf[u2] + Pf[u2 + 2560] + Pf[u2 + 5120] + Pf[u2 + 7680]);
}

// ---------------------------------------------------------------------------
// Kernel 3: bordered 54x54 rank-8 blocked elimination (6 phases + 6x6 tail).
// One block per channel; first sums the 8 Gram replicas (10 KB) into LDS.
// M = [[pr_cov+aI, B^T],[B, la_cov+aI]]; pivots 27..53 = chol(appro+aI)^2.
// ---------------------------------------------------------------------------
#define MS 56   // row stride (doubles), even for 16-B alignment
__device__ inline double g54(const float* __restrict__ G, int R, int C) {
  int I = R >> 4, J = C >> 4;
  if (I > J) { int tt = R; R = C; C = tt; I = R >> 4; J = C >> 4; }
  int tile = 4 * I - ((I * (I - 1)) >> 1) + (J - I);
  int r = R & 15, c = C & 15;
  return (double)G[tile * 256 + (r & 3) * 64 + ((r >> 2) << 4) + c];
}

__device__ inline int tri_row(int u) {
  int a = (int)((sqrtf(8.0f * (float)u + 1.0f) - 1.0f) * 0.5f);
  while ((a + 1) * (a + 2) / 2 <= u) a++;
  while (a * (a + 1) / 2 > u) a--;
  return a;
}

__global__ __launch_bounds__(256) void stage2_kernel(
    const float* __restrict__ gacc, float* __restrict__ out) {
  __shared__ double M[54 * MS];
  __shared__ float gsf[2560];
  __shared__ double slv[27], spv[27], piv[54], lred[27];
  int ch = blockIdx.x, tid = threadIdx.x;
  const double Minv = 1.0 / (double)NVAL;
  const double alpha = 5e-4;

  // Sum the 8 replicas into LDS
  for (int u = tid; u < 2560; u += 256) {
    const float* p = gacc + ch * 2560 + u;
    float s = 0.0f;
    #pragma unroll
    for (int r = 0; r < NREP; r++) s += p[r * GSZ];
    gsf[u] = s;
  }
  __syncthreads();
  const float* G = gsf;

  if (tid < 27) { slv[tid] = g54(G, tid, 54); spv[tid] = g54(G, 27 + tid, 54); }
  __syncthreads();
  // Build lower triangle of bordered matrix: 0..26 = pr dims, 27..53 = la
  for (int u = tid; u < 1485; u += 256) {
    int a = tri_row(u);
    int b = u - a * (a + 1) / 2;               // b <= a
    double v;
    if (a < 27) {                               // pr-pr
      v = g54(G, 27 + a, 27 + b) - spv[a] * spv[b] * Minv + ((a == b) ? alpha : 0.0);
    } else if (b >= 27) {                       // la-la
      int d = a - 27, e = b - 27;
      v = g54(G, d, e) - slv[d] * slv[e] * Minv + ((d == e) ? alpha : 0.0);
    } else {                                    // la row, pr col
      v = g54(G, a - 27, 27 + b) - slv[a - 27] * spv[b] * Minv;
    }
    M[a * MS + b] = v;
  }
  __syncthreads();

  #pragma unroll 1
  for (int phase = 0; phase < 6; phase++) {
    int k0 = phase * 8;
    // Load lower 8x8 pivot block (broadcast reads), factor LDL^T in regs
    double P[8][8];
    #pragma unroll
    for (int k = 0; k < 8; k++)
      #pragma unroll
      for (int j = 0; j <= k; j++)
        P[k][j] = M[(k0 + k) * MS + (k0 + j)];
    double idv[8];
    #pragma unroll
    for (int k = 0; k < 8; k++) {
      idv[k] = 1.0 / P[k][k];
      #pragma unroll
      for (int i = k + 1; i < 8; i++) {
        double l = P[i][k] * idv[k];
        #pragma unroll
        for (int j = k + 1; j <= i; j++)
          P[i][j] -= l * P[j][k];
      }
      #pragma unroll
      for (int i = k + 1; i < 8; i++) P[i][k] *= idv[k];
    }
    if (tid == 0) {
      #pragma unroll
      for (int k = 0; k < 8; k++) piv[k0 + k] = P[k][k];
    }
    int bstart = k0 + 8, n = 54 - bstart;
    int ncell = n * (n + 1) / 2;
    for (int u = tid; u < ncell; u += 256) {
      int ii = tri_row(u);
      int jj = u - ii * (ii + 1) / 2;
      int i = bstart + ii, j = bstart + jj;
      // 16-B aligned vector loads of the 8-double borders
      const double2* Ai = (const double2*)(M + i * MS + k0);
      const double2* Bj = (const double2*)(M + j * MS + k0);
      double2 a01 = Ai[0], a23 = Ai[1], a45 = Ai[2], a67 = Ai[3];
      double2 b01 = Bj[0], b23 = Bj[1], b45 = Bj[2], b67 = Bj[3];
      double av[8] = {a01.x, a01.y, a23.x, a23.y, a45.x, a45.y, a67.x, a67.y};
      double bv[8] = {b01.x, b01.y, b23.x, b23.y, b45.x, b45.y, b67.x, b67.y};
      #pragma unroll
      for (int k = 1; k < 8; k++) {
        #pragma unroll
        for (int m = 0; m < k; m++) {
          av[k] -= P[k][m] * av[m];
          bv[k] -= P[k][m] * bv[m];
        }
      }
      double acc = 0.0;
      #pragma unroll
      for (int k = 0; k < 8; k++) acc += av[k] * (bv[k] * idv[k]);
      M[i * MS + j] -= acc;
    }
    __syncthreads();
  }

  // Tail: 6x6 trailing block, pivots 48..53
  if (tid == 0) {
    double T[6][6];
    #pragma unroll
    for (int k = 0; k < 6; k++)
      #pragma unroll
      for (int j = 0; j <= k; j++)
        T[k][j] = M[(48 + k) * MS + (48 + j)];
    #pragma unroll
    for (int k = 0; k < 6; k++) {
      double dk = T[k][k];
      piv[48 + k] = dk;
      double id = 1.0 / dk;
      #pragma unroll
      for (int i = k + 1; i < 6; i++) {
        double l = T[i][k] * id;
        #pragma unroll
        for (int j = k + 1; j <= i; j++)
          T[i][j] -= l * T[j][k];
      }
    }
  }
  __syncthreads();

  if (tid < 27) lred[tid] = log(sqrt(piv[27 + tid]) + 1e-8);
  __syncthreads();
  if (tid == 0) {
    double s = 0.0;
    for (int i = 0; i < 27; i++) s += lred[i];
    atomicAdd(out, (float)(s / 54.0));
  }
}

// ---------------------------------------------------------------------------
extern "C" void kernel_launch(void* const* d_in, const int* in_sizes, int n_in,
                              void* d_out, int out_size, void* d_ws, size_t ws_size,
                              hipStream_t stream) {
  const float* logits = (const float*)d_in[0];
  const int* labels = (const int*)d_in[1];
  float* out = (float*)d_out;

  // ws layout: gacc fp32 x 8 replicas (640 KB) | shifted bf16 (3.6 MB)
  float* gacc = (float*)d_ws;
  u16* shifted = (u16*)((char*)d_ws + 655360);

  pool_kernel<<<432, 256, 0, stream>>>(logits, labels, shifted, gacc, out);
  gram_kernel<<<1024, 256, 0, stream>>>(shifted, gacc);
  stage2_kernel<<<NCH, 256, 0, stream>>>(gacc, out);
}

// Round 13
// 108.779 us; speedup vs baseline: 1.1952x; 1.0123x over previous
//
#include <hip/hip_runtime.h>
#include <math.h>

// Problem constants
#define NVAL  97336           // 46^3 valid window positions
#define NCH   8               // N*C = 2*4 channels
#define NREP  4               // Gram accumulator replicas (atomic decorrelation)
#define GSZ   20480           // NCH * 2560 floats per replica

typedef unsigned short u16;
typedef unsigned int u32;
typedef __attribute__((ext_vector_type(8))) short bf16x8;
typedef __attribute__((ext_vector_type(4))) float f32x4;
typedef __attribute__((ext_vector_type(4))) unsigned int u32x4;

// LDS staging geometry (gram kernel, 4x4 base tile -> 6x6 staged lines)
#define LINE_B 336            // 3 copies * 112 B per (x,y,vol) z-line
#define COPY_B 112            // 48 bf16 (96 B) + 16 B pad (bank spread)
#define VOL_B  12096          // 36 lines * 336
#define GLINE_U16 48          // global line: single copy, 48 u16 (96 B)

// ---------------------------------------------------------------------------
// Kernel 1: fused sigmoid/one-hot + 2x2x2 max-pool -> bf16, single copy per
// z-line. Each thread computes TWO pooled z-cells (float4/int4 loads).
// Also zeroes out[] and the 4 Gram replicas (one slot per spare thread).
// ---------------------------------------------------------------------------
__global__ __launch_bounds__(256) void pool_kernel(
    const float* __restrict__ logits, const int* __restrict__ labels,
    u16* __restrict__ shifted, float* __restrict__ gacc,
    float* __restrict__ out) {
  int t = blockIdx.x * 256 + threadIdx.x;
  if (t == 0) out[0] = 0.0f;
  if (t < NREP * GSZ) gacc[t] = 0.0f;        // 81920 < 110592 threads
  // t -> (n, X, Y, Zp) ; Zp = pooled z pair index (covers pooled z 2Zp,2Zp+1)
  int Zp = t % 24; int tmp = t / 24;
  int Y = tmp % 48; tmp /= 48;
  int X = tmp % 48; int n = tmp / 48;
  int sb = (2 * X) * 9216 + (2 * Y) * 96 + 4 * Zp;   // raw base, 16B aligned
  const int4* lb4 = (const int4*)(labels + n * 884736 + sb);
  int4 La = lb4[0], Lb = lb4[24], Lc = lb4[2304], Ld = lb4[2328];
  #pragma unroll
  for (int c = 0; c < 4; c++) {
    const float4* lg4 = (const float4*)(logits + (size_t)(n * 4 + c) * 884736 + sb);
    float4 v0 = lg4[0], v1 = lg4[24], v2 = lg4[2304], v3 = lg4[2328];
    float mx0 = fmaxf(fmaxf(fmaxf(v0.x, v0.y), fmaxf(v1.x, v1.y)),
                      fmaxf(fmaxf(v2.x, v2.y), fmaxf(v3.x, v3.y)));
    float mx1 = fmaxf(fmaxf(fmaxf(v0.z, v0.w), fmaxf(v1.z, v1.w)),
                      fmaxf(fmaxf(v2.z, v2.w), fmaxf(v3.z, v3.w)));
    // max(sigmoid) == sigmoid(max); +1e-6 commutes with max
    float pr0 = 1.0f / (1.0f + expf(-mx0)) + 1e-6f;
    float pr1 = 1.0f / (1.0f + expf(-mx1)) + 1e-6f;
    int la0 = (La.x == c || La.y == c || Lb.x == c || Lb.y == c ||
               Lc.x == c || Lc.y == c || Ld.x == c || Ld.y == c);
    int la1 = (La.z == c || La.w == c || Lb.z == c || Lb.w == c ||
               Lc.z == c || Lc.w == c || Ld.z == c || Ld.w == c);
    u32 lapack = (la0 ? 0x3F80u : 0u) | (la1 ? 0x3F800000u : 0u);
    unsigned int q0 = __float_as_uint(pr0);        // round-to-nearest-even bf16
    unsigned int q1 = __float_as_uint(pr1);
    u32 p0 = (q0 + 0x7FFF + ((q0 >> 16) & 1)) >> 16;
    u32 p1 = (q1 + 0x7FFF + ((q1 >> 16) & 1)) & 0xFFFF0000u;
    u32 prpack = p0 | p1;
    int ch = n * 4 + c;
    int line = X * 48 + Y;
    ((u32*)shifted)[((size_t)(ch * 2 + 0) * 2304 + line) * 24 + Zp] = lapack;
    ((u32*)shifted)[((size_t)(ch * 2 + 1) * 2304 + line) * 24 + Zp] = prpack;
  }
}

// ---------------------------------------------------------------------------
// Kernel 2: Gram via MFMA. W rows 0-26 = la shifts, 27-53 = pr shifts,
// 54 = ones (row sums), 55-63 = zero. G = (mask.W) W^T, upper triangle as
// 10 16x16 tiles. Block = (ch, 4x4 xy base tile) -> 24 KB LDS, 6 blocks/CU.
// 3 z-shifted copies built in-register during staging. Flush: two-phase LDS
// merge (waves 0,1 write; 2,3 add), then fp32 atomics into replica bx&3.
// ---------------------------------------------------------------------------
#define MFMA16(A, B, C) __builtin_amdgcn_mfma_f32_16x16x32_bf16((A), (B), (C), 0, 0, 0)

#define STEP(BA, AM) do {                                                  \
    int _ba = (BA);                                                        \
    u32x4 ub0 = *(const u32x4*)(smem + _ba + laneC0);                      \
    u32x4 ub1 = *(const u32x4*)(smem + _ba + laneC1);                      \
    u32x4 ub2 = *(const u32x4*)(smem + _ba + laneC2);                      \
    u32x4 ub3 = *(const u32x4*)(smem + _ba + laneC3);                      \
    ub3 = iszero ? zer4 : (isones ? one4 : ub3);                           \
    u32x4 ua0 = ub0, ua1 = ub1, ua2 = ub2, ua3 = ub3;                      \
    ua0.w &= (AM); ua1.w &= (AM); ua2.w &= (AM); ua3.w &= (AM);            \
    bf16x8 A0 = __builtin_bit_cast(bf16x8, ua0);                           \
    bf16x8 A1 = __builtin_bit_cast(bf16x8, ua1);                           \
    bf16x8 A2 = __builtin_bit_cast(bf16x8, ua2);                           \
    bf16x8 A3 = __builtin_bit_cast(bf16x8, ua3);                           \
    bf16x8 B0 = __builtin_bit_cast(bf16x8, ub0);                           \
    bf16x8 B1 = __builtin_bit_cast(bf16x8, ub1);                           \
    bf16x8 B2 = __builtin_bit_cast(bf16x8, ub2);                           \
    bf16x8 B3 = __builtin_bit_cast(bf16x8, ub3);                           \
    acc0 = MFMA16(A0, B0, acc0);  acc1 = MFMA16(A0, B1, acc1);             \
    acc2 = MFMA16(A0, B2, acc2);  acc3 = MFMA16(A0, B3, acc3);             \
    acc4 = MFMA16(A1, B1, acc4);  acc5 = MFMA16(A1, B2, acc5);             \
    acc6 = MFMA16(A1, B3, acc6);  acc7 = MFMA16(A2, B2, acc7);             \
    acc8 = MFMA16(A2, B3, acc8);  acc9 = MFMA16(A3, B3, acc9);             \
  } while (0)

__global__ __launch_bounds__(256) void gram_kernel(
    const u16* __restrict__ shifted, float* __restrict__ gacc) {
  __shared__ __align__(16) unsigned char smem[24192];
  int bx = blockIdx.x;
  int ch = bx / 144, tile = bx - ch * 144;
  int xt = tile / 12, yt = tile - xt * 12;
  int X0 = xt * 4, Y0 = yt * 4;
  int tw = (xt == 11) ? 2 : 4, th = (yt == 11) ? 2 : 4;  // valid bases 0..45
  int tid = threadIdx.x;

  // Stage fixed 6x6 lines x 2 vols; build 3 shifted copies in-register.
  const u16* base = shifted + (size_t)ch * 2 * 2304 * GLINE_U16;
  for (int j = tid; j < 432; j += 256) {         // 72 lines * 6 chunks
    int chunk = j % 6; int li = j / 6;           // li 0..71
    int sy = li % 6; int t2 = li / 6; int sx = t2 % 6; int vol = t2 / 6;
    int gx = X0 + sx; if (gx > 47) gx = 47;      // clamp: garbage, never read
    int gy = Y0 + sy; if (gy > 47) gy = 47;
    const u32* src = (const u32*)(base +
        ((size_t)vol * 2304 + gx * 48 + gy) * GLINE_U16);
    u32x4 v = *(const u32x4*)(src + chunk * 4);
    u32 d4 = (chunk < 5) ? src[chunk * 4 + 4] : 0u;   // next dword; 0 at tail
    unsigned char* dstp = smem + vol * VOL_B + (sx * 6 + sy) * LINE_B + chunk * 16;
    *(u32x4*)(dstp) = v;                                       // copy dz=0
    u32x4 s1 = { (v.x >> 16) | (v.y << 16), (v.y >> 16) | (v.z << 16),
                 (v.z >> 16) | (v.w << 16), (v.w >> 16) | (d4 << 16) };
    *(u32x4*)(dstp + COPY_B) = s1;                             // copy dz=1
    u32x4 s2 = { v.y, v.z, v.w, d4 };
    *(u32x4*)(dstp + 2 * COPY_B) = s2;                         // copy dz=2
  }
  __syncthreads();

  int lane = tid & 63, w = tid >> 6;
  int q = lane >> 4, rlo = lane & 15;
#define LANEC(F) ({ int _r = (F) * 16 + rlo; int _vol = 0, _s = 0;           \
    if (_r < 27) { _s = _r; } else if (_r < 54) { _vol = 1; _s = _r - 27; }  \
    int _dx = _s / 9, _dy = (_s / 3) % 3, _dz = _s % 3;                      \
    _vol * VOL_B + (_dx * 6 + _dy) * LINE_B + _dz * COPY_B; })
  int laneC0 = LANEC(0), laneC1 = LANEC(1), laneC2 = LANEC(2), laneC3 = LANEC(3);
  unsigned int am1 = (q == 1) ? 0u : ~0u;
  unsigned int am2 = (q == 3) ? 0u : ~0u;
  bool isones = (rlo == 6);    // frag3 row 54 = ones
  bool iszero = (rlo > 6);     // frag3 rows 55-63 = zero
  u32x4 one4 = {0x3F803F80u, 0x3F803F80u, 0x3F803F80u, 0x3F803F80u};
  u32x4 zer4 = {0u, 0u, 0u, 0u};

  f32x4 acc0 = {0,0,0,0}, acc1 = {0,0,0,0}, acc2 = {0,0,0,0}, acc3 = {0,0,0,0};
  f32x4 acc4 = {0,0,0,0}, acc5 = {0,0,0,0}, acc6 = {0,0,0,0}, acc7 = {0,0,0,0};
  f32x4 acc8 = {0,0,0,0}, acc9 = {0,0,0,0};

  int npl = (tw * th) >> 1;
  for (int pl = w; pl < npl; pl += 4) {
    int L0 = 2 * pl, L1 = L0 + 1;
    int lx0 = L0 / th, ly0 = L0 - lx0 * th;
    int lx1 = L1 / th, ly1 = L1 - lx1 * th;
    int U0 = (lx0 * 6 + ly0) * LINE_B;
    int U1 = (lx1 * 6 + ly1) * LINE_B;
    STEP(U0 + 16 * q, ~0u);
    STEP((q < 2) ? (U0 + 64 + 16 * q) : (U1 + 16 * q - 32), am1);
    STEP(U1 + 32 + 16 * q, am2);
  }
  __syncthreads();

  // Two-phase flush: waves 0,1 write regions 0,1; waves 2,3 add into them.
  float* Pf = (float*)smem;
#define FLW(T, A) { float* _qp = Pf + w * 2560 + (T) * 256 + lane;           \
    _qp[0] = (A).x; _qp[64] = (A).y; _qp[128] = (A).z; _qp[192] = (A).w; }
#define FLA(T, A) { float* _qp = Pf + (w - 2) * 2560 + (T) * 256 + lane;     \
    _qp[0] += (A).x; _qp[64] += (A).y; _qp[128] += (A).z; _qp[192] += (A).w; }
  if (w < 2) {
    FLW(0, acc0) FLW(1, acc1) FLW(2, acc2) FLW(3, acc3) FLW(4, acc4)
    FLW(5, acc5) FLW(6, acc6) FLW(7, acc7) FLW(8, acc8) FLW(9, acc9)
  }
  __syncthreads();
  if (w >= 2) {
    FLA(0, acc0) FLA(1, acc1) FLA(2, acc2) FLA(3, acc3) FLA(4, acc4)
    FLA(5, acc5) FLA(6, acc6) FLA(7, acc7) FLA(8, acc8) FLA(9, acc9)
  }
  __syncthreads();
  float* dst = gacc + (bx & 3) * GSZ + ch * 2560;
  for (int u2 = tid; u2 < 2560; u2 += 256)
    atomicAdd(&dst[u2], Pf[u2] + Pf[u2 + 2560]);
}

// ---------------------------------------------------------------------------
// Kernel 3: bordered 54x54 rank-8 blocked elimination (6 phases + 6x6 tail).
// One block per channel; first sums the 4 Gram replicas (10 KB) into LDS.
// M = [[pr_cov+aI, B^T],[B, la_cov+aI]]; pivots 27..53 = chol(appro+aI)^2.
// ---------------------------------------------------------------------------
#define MS 56   // row stride (doubles), even for 16-B alignment
__device__ inline double g54(const float* __restrict__ G, int R, int C) {
  int I = R >> 4, J = C >> 4;
  if (I > J) { int tt = R; R = C; C = tt; I = R >> 4; J = C >> 4; }
  int tile = 4 * I - ((I * (I - 1)) >> 1) + (J - I);
  int r = R & 15, c = C & 15;
  return (double)G[tile * 256 + (r & 3) * 64 + ((r >> 2) << 4) + c];
}

__device__ inline int tri_row(int u) {
  int a = (int)((sqrtf(8.0f * (float)u + 1.0f) - 1.0f) * 0.5f);
  while ((a + 1) * (a + 2) / 2 <= u) a++;
  while (a * (a + 1) / 2 > u) a--;
  return a;
}

__global__ __launch_bounds__(256) void stage2_kernel(
    const float* __restrict__ gacc, float* __restrict__ out) {
  __shared__ double M[54 * MS];
  __shared__ float gsf[2560];
  __shared__ double slv[27], spv[27], piv[54], lred[27];
  int ch = blockIdx.x, tid = threadIdx.x;
  const double Minv = 1.0 / (double)NVAL;
  const double alpha = 5e-4;

  // Sum the 4 replicas into LDS
  for (int u = tid; u < 2560; u += 256) {
    const float* p = gacc + ch * 2560 + u;
    float s = 0.0f;
    #pragma unroll
    for (int r = 0; r < NREP; r++) s += p[r * GSZ];
    gsf[u] = s;
  }
  __syncthreads();
  const float* G = gsf;

  if (tid < 27) { slv[tid] = g54(G, tid, 54); spv[tid] = g54(G, 27 + tid, 54); }
  __syncthreads();
  // Build lower triangle of bordered matrix: 0..26 = pr dims, 27..53 = la
  for (int u = tid; u < 1485; u += 256) {
    int a = tri_row(u);
    int b = u - a * (a + 1) / 2;               // b <= a
    double v;
    if (a < 27) {                               // pr-pr
      v = g54(G, 27 + a, 27 + b) - spv[a] * spv[b] * Minv + ((a == b) ? alpha : 0.0);
    } else if (b >= 27) {                       // la-la
      int d = a - 27, e = b - 27;
      v = g54(G, d, e) - slv[d] * slv[e] * Minv + ((d == e) ? alpha : 0.0);
    } else {                                    // la row, pr col
      v = g54(G, a - 27, 27 + b) - slv[a - 27] * spv[b] * Minv;
    }
    M[a * MS + b] = v;
  }
  __syncthreads();

  #pragma unroll 1
  for (int phase = 0; phase < 6; phase++) {
    int k0 = phase * 8;
    // Load lower 8x8 pivot block (broadcast reads), factor LDL^T in regs
    double P[8][8];
    #pragma unroll
    for (int k = 0; k < 8; k++)
      #pragma unroll
      for (int j = 0; j <= k; j++)
        P[k][j] = M[(k0 + k) * MS + (k0 + j)];
    double idv[8];
    #pragma unroll
    for (int k = 0; k < 8; k++) {
      idv[k] = 1.0 / P[k][k];
      #pragma unroll
      for (int i = k + 1; i < 8; i++) {
        double l = P[i][k] * idv[k];
        #pragma unroll
        for (int j = k + 1; j <= i; j++)
          P[i][j] -= l * P[j][k];
      }
      #pragma unroll
      for (int i = k + 1; i < 8; i++) P[i][k] *= idv[k];
    }
    if (tid == 0) {
      #pragma unroll
      for (int k = 0; k < 8; k++) piv[k0 + k] = P[k][k];
    }
    int bstart = k0 + 8, n = 54 - bstart;
    int ncell = n * (n + 1) / 2;
    for (int u = tid; u < ncell; u += 256) {
      int ii = tri_row(u);
      int jj = u - ii * (ii + 1) / 2;
      int i = bstart + ii, j = bstart + jj;
      // 16-B aligned vector loads of the 8-double borders
      const double2* Ai = (const double2*)(M + i * MS + k0);
      const double2* Bj = (const double2*)(M + j * MS + k0);
      double2 a01 = Ai[0], a23 = Ai[1], a45 = Ai[2], a67 = Ai[3];
      double2 b01 = Bj[0], b23 = Bj[1], b45 = Bj[2], b67 = Bj[3];
      double av[8] = {a01.x, a01.y, a23.x, a23.y, a45.x, a45.y, a67.x, a67.y};
      double bv[8] = {b01.x, b01.y, b23.x, b23.y, b45.x, b45.y, b67.x, b67.y};
      #pragma unroll
      for (int k = 1; k < 8; k++) {
        #pragma unroll
        for (int m = 0; m < k; m++) {
          av[k] -= P[k][m] * av[m];
          bv[k] -= P[k][m] * bv[m];
        }
      }
      double acc = 0.0;
      #pragma unroll
      for (int k = 0; k < 8; k++) acc += av[k] * (bv[k] * idv[k]);
      M[i * MS + j] -= acc;
    }
    __syncthreads();
  }

  // Tail: 6x6 trailing block, pivots 48..53
  if (tid == 0) {
    double T[6][6];
    #pragma unroll
    for (int k = 0; k < 6; k++)
      #pragma unroll
      for (int j = 0; j <= k; j++)
        T[k][j] = M[(48 + k) * MS + (48 + j)];
    #pragma unroll
    for (int k = 0; k < 6; k++) {
      double dk = T[k][k];
      piv[48 + k] = dk;
      double id = 1.0 / dk;
      #pragma unroll
      for (int i = k + 1; i < 6; i++) {
        double l = T[i][k] * id;
        #pragma unroll
        for (int j = k + 1; j <= i; j++)
          T[i][j] -= l * T[j][k];
      }
    }
  }
  __syncthreads();

  if (tid < 27) lred[tid] = log(sqrt(piv[27 + tid]) + 1e-8);
  __syncthreads();
  if (tid == 0) {
    double s = 0.0;
    for (int i = 0; i < 27; i++) s += lred[i];
    atomicAdd(out, (float)(s / 54.0));
  }
}

// ---------------------------------------------------------------------------
extern "C" void kernel_launch(void* const* d_in, const int* in_sizes, int n_in,
                              void* d_out, int out_size, void* d_ws, size_t ws_size,
                              hipStream_t stream) {
  const float* logits = (const float*)d_in[0];
  const int* labels = (const int*)d_in[1];
  float* out = (float*)d_out;

  // ws layout: gacc fp32 x 4 replicas (320 KB) | shifted bf16 (3.6 MB)
  float* gacc = (float*)d_ws;
  u16* shifted = (u16*)((char*)d_ws + 327680);

  pool_kernel<<<432, 256, 0, stream>>>(logits, labels, shifted, gacc, out);
  gram_kernel<<<NCH * 144, 256, 0, stream>>>(shifted, gacc);
  stage2_kernel<<<NCH, 256, 0, stream>>>(gacc, out);
}

// Round 14
// 102.611 us; speedup vs baseline: 1.2670x; 1.0601x over previous
//
#include <hip/hip_runtime.h>
#include <math.h>

// Problem constants
#define NVAL  97336           // 46^3 valid window positions
#define NCH   8               // N*C = 2*4 channels

typedef unsigned short u16;
typedef unsigned int u32;
typedef __attribute__((ext_vector_type(8))) short bf16x8;
typedef __attribute__((ext_vector_type(4))) float f32x4;
typedef __attribute__((ext_vector_type(4))) unsigned int u32x4;

// LDS staging geometry (gram kernel)
#define LINE_B 336            // 3 copies * 112 B per (x,y,vol) z-line
#define COPY_B 112            // 48 bf16 (96 B) + 16 B pad (bank spread)
#define VOL_B  21504          // 64 lines * 336
#define GLINE_U16 48          // global line: single copy, 48 u16 (96 B)

// ---------------------------------------------------------------------------
// Kernel 1: fused sigmoid/one-hot + 2x2x2 max-pool -> bf16, single copy per
// z-line. Each thread computes TWO pooled z-cells (float4/int4 loads).
// Also zeroes out[] (thread 0) and the fp32 Gram accumulator (t < 20480).
// ---------------------------------------------------------------------------
__global__ __launch_bounds__(256) void pool_kernel(
    const float* __restrict__ logits, const int* __restrict__ labels,
    u16* __restrict__ shifted, float* __restrict__ gacc,
    float* __restrict__ out) {
  int t = blockIdx.x * 256 + threadIdx.x;
  if (t == 0) out[0] = 0.0f;
  if (t < NCH * 2560) gacc[t] = 0.0f;        // 20480 < 110592 threads
  // t -> (n, X, Y, Zp) ; Zp = pooled z pair index (covers pooled z 2Zp,2Zp+1)
  int Zp = t % 24; int tmp = t / 24;
  int Y = tmp % 48; tmp /= 48;
  int X = tmp % 48; int n = tmp / 48;
  int sb = (2 * X) * 9216 + (2 * Y) * 96 + 4 * Zp;   // raw base, 16B aligned
  const int4* lb4 = (const int4*)(labels + n * 884736 + sb);
  int4 La = lb4[0], Lb = lb4[24], Lc = lb4[2304], Ld = lb4[2328];
  #pragma unroll
  for (int c = 0; c < 4; c++) {
    const float4* lg4 = (const float4*)(logits + (size_t)(n * 4 + c) * 884736 + sb);
    float4 v0 = lg4[0], v1 = lg4[24], v2 = lg4[2304], v3 = lg4[2328];
    float mx0 = fmaxf(fmaxf(fmaxf(v0.x, v0.y), fmaxf(v1.x, v1.y)),
                      fmaxf(fmaxf(v2.x, v2.y), fmaxf(v3.x, v3.y)));
    float mx1 = fmaxf(fmaxf(fmaxf(v0.z, v0.w), fmaxf(v1.z, v1.w)),
                      fmaxf(fmaxf(v2.z, v2.w), fmaxf(v3.z, v3.w)));
    // max(sigmoid) == sigmoid(max); +1e-6 commutes with max
    float pr0 = 1.0f / (1.0f + expf(-mx0)) + 1e-6f;
    float pr1 = 1.0f / (1.0f + expf(-mx1)) + 1e-6f;
    int la0 = (La.x == c || La.y == c || Lb.x == c || Lb.y == c ||
               Lc.x == c || Lc.y == c || Ld.x == c || Ld.y == c);
    int la1 = (La.z == c || La.w == c || Lb.z == c || Lb.w == c ||
               Lc.z == c || Lc.w == c || Ld.z == c || Ld.w == c);
    u32 lapack = (la0 ? 0x3F80u : 0u) | (la1 ? 0x3F800000u : 0u);
    unsigned int q0 = __float_as_uint(pr0);        // round-to-nearest-even bf16
    unsigned int q1 = __float_as_uint(pr1);
    u32 p0 = (q0 + 0x7FFF + ((q0 >> 16) & 1)) >> 16;
    u32 p1 = (q1 + 0x7FFF + ((q1 >> 16) & 1)) & 0xFFFF0000u;
    u32 prpack = p0 | p1;
    int ch = n * 4 + c;
    int line = X * 48 + Y;
    ((u32*)shifted)[((size_t)(ch * 2 + 0) * 2304 + line) * 24 + Zp] = lapack;
    ((u32*)shifted)[((size_t)(ch * 2 + 1) * 2304 + line) * 24 + Zp] = prpack;
  }
}

// ---------------------------------------------------------------------------
// Kernel 2: Gram via MFMA (R10-verified structure). W rows 0-26 = la shifts,
// 27-53 = pr shifts, 54 = ones (row sums), 55-63 = zero. G = (mask.W) W^T,
// upper triangle as 10 16x16 tiles. Block = (ch, 6x6 xy-tile). 3 z-shifted
// copies built in-register during staging; fp32 atomics into per-ch Gram.
// ---------------------------------------------------------------------------
#define MFMA16(A, B, C) __builtin_amdgcn_mfma_f32_16x16x32_bf16((A), (B), (C), 0, 0, 0)

#define STEP(BA, AM) do {                                                  \
    int _ba = (BA);                                                        \
    u32x4 ub0 = *(const u32x4*)(smem + _ba + laneC0);                      \
    u32x4 ub1 = *(const u32x4*)(smem + _ba + laneC1);                      \
    u32x4 ub2 = *(const u32x4*)(smem + _ba + laneC2);                      \
    u32x4 ub3 = *(const u32x4*)(smem + _ba + laneC3);                      \
    ub3 = iszero ? zer4 : (isones ? one4 : ub3);                           \
    u32x4 ua0 = ub0, ua1 = ub1, ua2 = ub2, ua3 = ub3;                      \
    ua0.w &= (AM); ua1.w &= (AM); ua2.w &= (AM); ua3.w &= (AM);            \
    bf16x8 A0 = __builtin_bit_cast(bf16x8, ua0);                           \
    bf16x8 A1 = __builtin_bit_cast(bf16x8, ua1);                           \
    bf16x8 A2 = __builtin_bit_cast(bf16x8, ua2);                           \
    bf16x8 A3 = __builtin_bit_cast(bf16x8, ua3);                           \
    bf16x8 B0 = __builtin_bit_cast(bf16x8, ub0);                           \
    bf16x8 B1 = __builtin_bit_cast(bf16x8, ub1);                           \
    bf16x8 B2 = __builtin_bit_cast(bf16x8, ub2);                           \
    bf16x8 B3 = __builtin_bit_cast(bf16x8, ub3);                           \
    acc0 = MFMA16(A0, B0, acc0);  acc1 = MFMA16(A0, B1, acc1);             \
    acc2 = MFMA16(A0, B2, acc2);  acc3 = MFMA16(A0, B3, acc3);             \
    acc4 = MFMA16(A1, B1, acc4);  acc5 = MFMA16(A1, B2, acc5);             \
    acc6 = MFMA16(A1, B3, acc6);  acc7 = MFMA16(A2, B2, acc7);             \
    acc8 = MFMA16(A2, B3, acc8);  acc9 = MFMA16(A3, B3, acc9);             \
  } while (0)

__global__ __launch_bounds__(256) void gram_kernel(
    const u16* __restrict__ shifted, float* __restrict__ gacc) {
  __shared__ __align__(16) unsigned char smem[43008];
  int bx = blockIdx.x;
  int ch = bx >> 6, xt = (bx >> 3) & 7, yt = bx & 7;
  int X0 = xt * 6, Y0 = yt * 6;
  int tw = (xt == 7) ? 4 : 6, th = (yt == 7) ? 4 : 6;
  int tid = threadIdx.x;

  // Stage fixed 8x8 lines x 2 vols; build 3 shifted copies in-register.
  const u16* base = shifted + (size_t)ch * 2 * 2304 * GLINE_U16;
  for (int j = tid; j < 768; j += 256) {         // 128 lines * 6 chunks
    int chunk = j % 6; int li = j / 6;           // li 0..127
    int sy = li & 7, sx = (li >> 3) & 7, vol = li >> 6;
    int gx = X0 + sx; if (gx > 47) gx = 47;      // clamp: garbage, never read
    int gy = Y0 + sy; if (gy > 47) gy = 47;
    const u32* src = (const u32*)(base +
        ((size_t)vol * 2304 + gx * 48 + gy) * GLINE_U16);
    u32x4 v = *(const u32x4*)(src + chunk * 4);
    u32 d4 = (chunk < 5) ? src[chunk * 4 + 4] : 0u;   // next dword; 0 at tail
    unsigned char* dstp = smem + vol * VOL_B + ((sx << 3) + sy) * LINE_B + chunk * 16;
    *(u32x4*)(dstp) = v;                                       // copy dz=0
    u32x4 s1 = { (v.x >> 16) | (v.y << 16), (v.y >> 16) | (v.z << 16),
                 (v.z >> 16) | (v.w << 16), (v.w >> 16) | (d4 << 16) };
    *(u32x4*)(dstp + COPY_B) = s1;                             // copy dz=1
    u32x4 s2 = { v.y, v.z, v.w, d4 };
    *(u32x4*)(dstp + 2 * COPY_B) = s2;                         // copy dz=2
  }
  __syncthreads();

  int lane = tid & 63, w = tid >> 6;
  int q = lane >> 4, rlo = lane & 15;
#define LANEC(F) ({ int _r = (F) * 16 + rlo; int _vol = 0, _s = 0;           \
    if (_r < 27) { _s = _r; } else if (_r < 54) { _vol = 1; _s = _r - 27; }  \
    int _dx = _s / 9, _dy = (_s / 3) % 3, _dz = _s % 3;                      \
    _vol * VOL_B + ((_dx << 3) + _dy) * LINE_B + _dz * COPY_B; })
  int laneC0 = LANEC(0), laneC1 = LANEC(1), laneC2 = LANEC(2), laneC3 = LANEC(3);
  unsigned int am1 = (q == 1) ? 0u : ~0u;
  unsigned int am2 = (q == 3) ? 0u : ~0u;
  bool isones = (rlo == 6);    // frag3 row 54 = ones
  bool iszero = (rlo > 6);     // frag3 rows 55-63 = zero
  u32x4 one4 = {0x3F803F80u, 0x3F803F80u, 0x3F803F80u, 0x3F803F80u};
  u32x4 zer4 = {0u, 0u, 0u, 0u};

  f32x4 acc0 = {0,0,0,0}, acc1 = {0,0,0,0}, acc2 = {0,0,0,0}, acc3 = {0,0,0,0};
  f32x4 acc4 = {0,0,0,0}, acc5 = {0,0,0,0}, acc6 = {0,0,0,0}, acc7 = {0,0,0,0};
  f32x4 acc8 = {0,0,0,0}, acc9 = {0,0,0,0};

  int npl = (tw * th) >> 1;
  for (int pl = w; pl < npl; pl += 4) {
    int L0 = 2 * pl, L1 = L0 + 1;
    int lx0 = L0 / th, ly0 = L0 - lx0 * th;
    int lx1 = L1 / th, ly1 = L1 - lx1 * th;
    int U0 = ((lx0 << 3) + ly0) * LINE_B;
    int U1 = ((lx1 << 3) + ly1) * LINE_B;
    STEP(U0 + 16 * q, ~0u);
    STEP((q < 2) ? (U0 + 64 + 16 * q) : (U1 + 16 * q - 32), am1);
    STEP(U1 + 32 + 16 * q, am2);
  }
  __syncthreads();

  float* Pf = (float*)smem;
#define FL(T, A) { float* _qp = Pf + w * 2560 + (T) * 256 + lane;            \
    _qp[0] = (A).x; _qp[64] = (A).y; _qp[128] = (A).z; _qp[192] = (A).w; }
  FL(0, acc0) FL(1, acc1) FL(2, acc2) FL(3, acc3) FL(4, acc4)
  FL(5, acc5) FL(6, acc6) FL(7, acc7) FL(8, acc8) FL(9, acc9)
  __syncthreads();
  float* dst = gacc + (size_t)ch * 2560;
  for (int u2 = tid; u2 < 2560; u2 += 256)
    atomicAdd(&dst[u2], Pf[u2] + Pf[u2 + 2560] + Pf[u2 + 5120] + Pf[u2 + 7680]);
}

// ---------------------------------------------------------------------------
// Kernel 3: bordered 54x54 rank-8 blocked elimination (6 phases + 6x6 tail).
// One block per channel, reading the fp32 global Gram (10 KB, L2-resident).
// M = [[pr_cov+aI, B^T],[B, la_cov+aI]]; pivots 27..53 = chol(appro+aI)^2.
// ---------------------------------------------------------------------------
#define MS 56   // row stride (doubles), even for 16-B alignment
__device__ inline double g54(const float* __restrict__ G, int R, int C) {
  int I = R >> 4, J = C >> 4;
  if (I > J) { int tt = R; R = C; C = tt; I = R >> 4; J = C >> 4; }
  int tile = 4 * I - ((I * (I - 1)) >> 1) + (J - I);
  int r = R & 15, c = C & 15;
  return (double)G[tile * 256 + (r & 3) * 64 + ((r >> 2) << 4) + c];
}

__device__ inline int tri_row(int u) {
  int a = (int)((sqrtf(8.0f * (float)u + 1.0f) - 1.0f) * 0.5f);
  while ((a + 1) * (a + 2) / 2 <= u) a++;
  while (a * (a + 1) / 2 > u) a--;
  return a;
}

__global__ __launch_bounds__(256) void stage2_kernel(
    const float* __restrict__ gacc, float* __restrict__ out) {
  __shared__ double M[54 * MS];
  __shared__ double slv[27], spv[27], piv[54], lred[27];
  int ch = blockIdx.x, tid = threadIdx.x;
  const double Minv = 1.0 / (double)NVAL;
  const double alpha = 5e-4;
  const float* G = gacc + (size_t)ch * 2560;

  if (tid < 27) { slv[tid] = g54(G, tid, 54); spv[tid] = g54(G, 27 + tid, 54); }
  __syncthreads();
  // Build lower triangle of bordered matrix: 0..26 = pr dims, 27..53 = la
  for (int u = tid; u < 1485; u += 256) {
    int a = tri_row(u);
    int b = u - a * (a + 1) / 2;               // b <= a
    double v;
    if (a < 27) {                               // pr-pr
      v = g54(G, 27 + a, 27 + b) - spv[a] * spv[b] * Minv + ((a == b) ? alpha : 0.0);
    } else if (b >= 27) {                       // la-la
      int d = a - 27, e = b - 27;
      v = g54(G, d, e) - slv[d] * slv[e] * Minv + ((d == e) ? alpha : 0.0);
    } else {                                    // la row, pr col
      v = g54(G, a - 27, 27 + b) - slv[a - 27] * spv[b] * Minv;
    }
    M[a * MS + b] = v;
  }
  __syncthreads();

  #pragma unroll 1
  for (int phase = 0; phase < 6; phase++) {
    int k0 = phase * 8;
    // Load lower 8x8 pivot block (broadcast reads), factor LDL^T in regs
    double P[8][8];
    #pragma unroll
    for (int k = 0; k < 8; k++)
      #pragma unroll
      for (int j = 0; j <= k; j++)
        P[k][j] = M[(k0 + k) * MS + (k0 + j)];
    double idv[8];
    #pragma unroll
    for (int k = 0; k < 8; k++) {
      idv[k] = 1.0 / P[k][k];
      #pragma unroll
      for (int i = k + 1; i < 8; i++) {
        double l = P[i][k] * idv[k];
        #pragma unroll
        for (int j = k + 1; j <= i; j++)
          P[i][j] -= l * P[j][k];
      }
      #pragma unroll
      for (int i = k + 1; i < 8; i++) P[i][k] *= idv[k];
    }
    if (tid == 0) {
      #pragma unroll
      for (int k = 0; k < 8; k++) piv[k0 + k] = P[k][k];
    }
    int bstart = k0 + 8, n = 54 - bstart;
    int ncell = n * (n + 1) / 2;
    for (int u = tid; u < ncell; u += 256) {
      int ii = tri_row(u);
      int jj = u - ii * (ii + 1) / 2;
      int i = bstart + ii, j = bstart + jj;
      // 16-B aligned vector loads of the 8-double borders
      const double2* Ai = (const double2*)(M + i * MS + k0);
      const double2* Bj = (const double2*)(M + j * MS + k0);
      double2 a01 = Ai[0], a23 = Ai[1], a45 = Ai[2], a67 = Ai[3];
      double2 b01 = Bj[0], b23 = Bj[1], b45 = Bj[2], b67 = Bj[3];
      double av[8] = {a01.x, a01.y, a23.x, a23.y, a45.x, a45.y, a67.x, a67.y};
      double bv[8] = {b01.x, b01.y, b23.x, b23.y, b45.x, b45.y, b67.x, b67.y};
      #pragma unroll
      for (int k = 1; k < 8; k++) {
        #pragma unroll
        for (int m = 0; m < k; m++) {
          av[k] -= P[k][m] * av[m];
          bv[k] -= P[k][m] * bv[m];
        }
      }
      double acc = 0.0;
      #pragma unroll
      for (int k = 0; k < 8; k++) acc += av[k] * (bv[k] * idv[k]);
      M[i * MS + j] -= acc;
    }
    __syncthreads();
  }

  // Tail: 6x6 trailing block, pivots 48..53
  if (tid == 0) {
    double T[6][6];
    #pragma unroll
    for (int k = 0; k < 6; k++)
      #pragma unroll
      for (int j = 0; j <= k; j++)
        T[k][j] = M[(48 + k) * MS + (48 + j)];
    #pragma unroll
    for (int k = 0; k < 6; k++) {
      double dk = T[k][k];
      piv[48 + k] = dk;
      double id = 1.0 / dk;
      #pragma unroll
      for (int i = k + 1; i < 6; i++) {
        double l = T[i][k] * id;
        #pragma unroll
        for (int j = k + 1; j <= i; j++)
          T[i][j] -= l * T[j][k];
      }
    }
  }
  __syncthreads();

  if (tid < 27) lred[tid] = log(sqrt(piv[27 + tid]) + 1e-8);
  __syncthreads();
  if (tid == 0) {
    double s = 0.0;
    for (int i = 0; i < 27; i++) s += lred[i];
    atomicAdd(out, (float)(s / 54.0));
  }
}

// ---------------------------------------------------------------------------
extern "C" void kernel_launch(void* const* d_in, const int* in_sizes, int n_in,
                              void* d_out, int out_size, void* d_ws, size_t ws_size,
                              hipStream_t stream) {
  const float* logits = (const float*)d_in[0];
  const int* labels = (const int*)d_in[1];
  float* out = (float*)d_out;

  // ws layout: gacc fp32 (80 KB, zeroed by pool) | shifted bf16 (3.6 MB)
  float* gacc = (float*)d_ws;
  u16* shifted = (u16*)((char*)d_ws + 131072);

  pool_kernel<<<432, 256, 0, stream>>>(logits, labels, shifted, gacc, out);
  gram_kernel<<<512, 256, 0, stream>>>(shifted, gacc);
  stage2_kernel<<<NCH, 256, 0, stream>>>(gacc, out);
}

// Round 15
// 102.528 us; speedup vs baseline: 1.2681x; 1.0008x over previous
//
#include <hip/hip_runtime.h>
#include <math.h>

// Problem constants
#define NVAL  97336           // 46^3 valid window positions
#define NCH   8               // N*C = 2*4 channels
#define NREP  4               // Gram accumulator replicas (atomic decorrelation)
#define GSZ   20480           // NCH * 2560 floats per replica

typedef unsigned short u16;
typedef unsigned int u32;
typedef __attribute__((ext_vector_type(8))) short bf16x8;
typedef __attribute__((ext_vector_type(4))) float f32x4;
typedef __attribute__((ext_vector_type(4))) unsigned int u32x4;

// LDS staging geometry (gram kernel)
#define LINE_B 336            // 3 copies * 112 B per (x,y,vol) z-line
#define COPY_B 112            // 48 bf16 (96 B) + 16 B pad (bank spread)
#define VOL_B  21504          // 64 lines * 336
#define GLINE_U16 48          // global line: single copy, 48 u16 (96 B)

// ---------------------------------------------------------------------------
// Kernel 1: fused sigmoid/one-hot + 2x2x2 max-pool -> bf16, single copy per
// z-line. Each thread computes TWO pooled z-cells (float4/int4 loads).
// Also zeroes out[] (thread 0) and the 4 Gram replicas (t < 81920).
// ---------------------------------------------------------------------------
__global__ __launch_bounds__(256) void pool_kernel(
    const float* __restrict__ logits, const int* __restrict__ labels,
    u16* __restrict__ shifted, float* __restrict__ gacc,
    float* __restrict__ out) {
  int t = blockIdx.x * 256 + threadIdx.x;
  if (t == 0) out[0] = 0.0f;
  if (t < NREP * GSZ) gacc[t] = 0.0f;        // 81920 < 110592 threads
  // t -> (n, X, Y, Zp) ; Zp = pooled z pair index (covers pooled z 2Zp,2Zp+1)
  int Zp = t % 24; int tmp = t / 24;
  int Y = tmp % 48; tmp /= 48;
  int X = tmp % 48; int n = tmp / 48;
  int sb = (2 * X) * 9216 + (2 * Y) * 96 + 4 * Zp;   // raw base, 16B aligned
  const int4* lb4 = (const int4*)(labels + n * 884736 + sb);
  int4 La = lb4[0], Lb = lb4[24], Lc = lb4[2304], Ld = lb4[2328];
  #pragma unroll
  for (int c = 0; c < 4; c++) {
    const float4* lg4 = (const float4*)(logits + (size_t)(n * 4 + c) * 884736 + sb);
    float4 v0 = lg4[0], v1 = lg4[24], v2 = lg4[2304], v3 = lg4[2328];
    float mx0 = fmaxf(fmaxf(fmaxf(v0.x, v0.y), fmaxf(v1.x, v1.y)),
                      fmaxf(fmaxf(v2.x, v2.y), fmaxf(v3.x, v3.y)));
    float mx1 = fmaxf(fmaxf(fmaxf(v0.z, v0.w), fmaxf(v1.z, v1.w)),
                      fmaxf(fmaxf(v2.z, v2.w), fmaxf(v3.z, v3.w)));
    // max(sigmoid) == sigmoid(max); +1e-6 commutes with max
    float pr0 = 1.0f / (1.0f + expf(-mx0)) + 1e-6f;
    float pr1 = 1.0f / (1.0f + expf(-mx1)) + 1e-6f;
    int la0 = (La.x == c || La.y == c || Lb.x == c || Lb.y == c ||
               Lc.x == c || Lc.y == c || Ld.x == c || Ld.y == c);
    int la1 = (La.z == c || La.w == c || Lb.z == c || Lb.w == c ||
               Lc.z == c || Lc.w == c || Ld.z == c || Ld.w == c);
    u32 lapack = (la0 ? 0x3F80u : 0u) | (la1 ? 0x3F800000u : 0u);
    unsigned int q0 = __float_as_uint(pr0);        // round-to-nearest-even bf16
    unsigned int q1 = __float_as_uint(pr1);
    u32 p0 = (q0 + 0x7FFF + ((q0 >> 16) & 1)) >> 16;
    u32 p1 = (q1 + 0x7FFF + ((q1 >> 16) & 1)) & 0xFFFF0000u;
    u32 prpack = p0 | p1;
    int ch = n * 4 + c;
    int line = X * 48 + Y;
    ((u32*)shifted)[((size_t)(ch * 2 + 0) * 2304 + line) * 24 + Zp] = lapack;
    ((u32*)shifted)[((size_t)(ch * 2 + 1) * 2304 + line) * 24 + Zp] = prpack;
  }
}

// ---------------------------------------------------------------------------
// Kernel 2: Gram via MFMA (R10-verified structure). W rows 0-26 = la shifts,
// 27-53 = pr shifts, 54 = ones (row sums), 55-63 = zero. G = (mask.W) W^T,
// upper triangle as 10 16x16 tiles. Block = (ch, 6x6 xy-tile). 3 z-shifted
// copies built in-register during staging; fp32 atomics into replica bx&3
// (16-way max same-address contention instead of 64-way).
// ---------------------------------------------------------------------------
#define MFMA16(A, B, C) __builtin_amdgcn_mfma_f32_16x16x32_bf16((A), (B), (C), 0, 0, 0)

#define STEP(BA, AM) do {                                                  \
    int _ba = (BA);                                                        \
    u32x4 ub0 = *(const u32x4*)(smem + _ba + laneC0);                      \
    u32x4 ub1 = *(const u32x4*)(smem + _ba + laneC1);                      \
    u32x4 ub2 = *(const u32x4*)(smem + _ba + laneC2);                      \
    u32x4 ub3 = *(const u32x4*)(smem + _ba + laneC3);                      \
    ub3 = iszero ? zer4 : (isones ? one4 : ub3);                           \
    u32x4 ua0 = ub0, ua1 = ub1, ua2 = ub2, ua3 = ub3;                      \
    ua0.w &= (AM); ua1.w &= (AM); ua2.w &= (AM); ua3.w &= (AM);            \
    bf16x8 A0 = __builtin_bit_cast(bf16x8, ua0);                           \
    bf16x8 A1 = __builtin_bit_cast(bf16x8, ua1);                           \
    bf16x8 A2 = __builtin_bit_cast(bf16x8, ua2);                           \
    bf16x8 A3 = __builtin_bit_cast(bf16x8, ua3);                           \
    bf16x8 B0 = __builtin_bit_cast(bf16x8, ub0);                           \
    bf16x8 B1 = __builtin_bit_cast(bf16x8, ub1);                           \
    bf16x8 B2 = __builtin_bit_cast(bf16x8, ub2);                           \
    bf16x8 B3 = __builtin_bit_cast(bf16x8, ub3);                           \
    acc0 = MFMA16(A0, B0, acc0);  acc1 = MFMA16(A0, B1, acc1);             \
    acc2 = MFMA16(A0, B2, acc2);  acc3 = MFMA16(A0, B3, acc3);             \
    acc4 = MFMA16(A1, B1, acc4);  acc5 = MFMA16(A1, B2, acc5);             \
    acc6 = MFMA16(A1, B3, acc6);  acc7 = MFMA16(A2, B2, acc7);             \
    acc8 = MFMA16(A2, B3, acc8);  acc9 = MFMA16(A3, B3, acc9);             \
  } while (0)

__global__ __launch_bounds__(256) void gram_kernel(
    const u16* __restrict__ shifted, float* __restrict__ gacc) {
  __shared__ __align__(16) unsigned char smem[43008];
  int bx = blockIdx.x;
  int ch = bx >> 6, xt = (bx >> 3) & 7, yt = bx & 7;
  int X0 = xt * 6, Y0 = yt * 6;
  int tw = (xt == 7) ? 4 : 6, th = (yt == 7) ? 4 : 6;
  int tid = threadIdx.x;

  // Stage fixed 8x8 lines x 2 vols; build 3 shifted copies in-register.
  const u16* base = shifted + (size_t)ch * 2 * 2304 * GLINE_U16;
  for (int j = tid; j < 768; j += 256) {         // 128 lines * 6 chunks
    int chunk = j % 6; int li = j / 6;           // li 0..127
    int sy = li & 7, sx = (li >> 3) & 7, vol = li >> 6;
    int gx = X0 + sx; if (gx > 47) gx = 47;      // clamp: garbage, never read
    int gy = Y0 + sy; if (gy > 47) gy = 47;
    const u32* src = (const u32*)(base +
        ((size_t)vol * 2304 + gx * 48 + gy) * GLINE_U16);
    u32x4 v = *(const u32x4*)(src + chunk * 4);
    u32 d4 = (chunk < 5) ? src[chunk * 4 + 4] : 0u;   // next dword; 0 at tail
    unsigned char* dstp = smem + vol * VOL_B + ((sx << 3) + sy) * LINE_B + chunk * 16;
    *(u32x4*)(dstp) = v;                                       // copy dz=0
    u32x4 s1 = { (v.x >> 16) | (v.y << 16), (v.y >> 16) | (v.z << 16),
                 (v.z >> 16) | (v.w << 16), (v.w >> 16) | (d4 << 16) };
    *(u32x4*)(dstp + COPY_B) = s1;                             // copy dz=1
    u32x4 s2 = { v.y, v.z, v.w, d4 };
    *(u32x4*)(dstp + 2 * COPY_B) = s2;                         // copy dz=2
  }
  __syncthreads();

  int lane = tid & 63, w = tid >> 6;
  int q = lane >> 4, rlo = lane & 15;
#define LANEC(F) ({ int _r = (F) * 16 + rlo; int _vol = 0, _s = 0;           \
    if (_r < 27) { _s = _r; } else if (_r < 54) { _vol = 1; _s = _r - 27; }  \
    int _dx = _s / 9, _dy = (_s / 3) % 3, _dz = _s % 3;                      \
    _vol * VOL_B + ((_dx << 3) + _dy) * LINE_B + _dz * COPY_B; })
  int laneC0 = LANEC(0), laneC1 = LANEC(1), laneC2 = LANEC(2), laneC3 = LANEC(3);
  unsigned int am1 = (q == 1) ? 0u : ~0u;
  unsigned int am2 = (q == 3) ? 0u : ~0u;
  bool isones = (rlo == 6);    // frag3 row 54 = ones
  bool iszero = (rlo > 6);     // frag3 rows 55-63 = zero
  u32x4 one4 = {0x3F803F80u, 0x3F803F80u, 0x3F803F80u, 0x3F803F80u};
  u32x4 zer4 = {0u, 0u, 0u, 0u};

  f32x4 acc0 = {0,0,0,0}, acc1 = {0,0,0,0}, acc2 = {0,0,0,0}, acc3 = {0,0,0,0};
  f32x4 acc4 = {0,0,0,0}, acc5 = {0,0,0,0}, acc6 = {0,0,0,0}, acc7 = {0,0,0,0};
  f32x4 acc8 = {0,0,0,0}, acc9 = {0,0,0,0};

  int npl = (tw * th) >> 1;
  for (int pl = w; pl < npl; pl += 4) {
    int L0 = 2 * pl, L1 = L0 + 1;
    int lx0 = L0 / th, ly0 = L0 - lx0 * th;
    int lx1 = L1 / th, ly1 = L1 - lx1 * th;
    int U0 = ((lx0 << 3) + ly0) * LINE_B;
    int U1 = ((lx1 << 3) + ly1) * LINE_B;
    STEP(U0 + 16 * q, ~0u);
    STEP((q < 2) ? (U0 + 64 + 16 * q) : (U1 + 16 * q - 32), am1);
    STEP(U1 + 32 + 16 * q, am2);
  }
  __syncthreads();

  float* Pf = (float*)smem;
#define FL(T, A) { float* _qp = Pf + w * 2560 + (T) * 256 + lane;            \
    _qp[0] = (A).x; _qp[64] = (A).y; _qp[128] = (A).z; _qp[192] = (A).w; }
  FL(0, acc0) FL(1, acc1) FL(2, acc2) FL(3, acc3) FL(4, acc4)
  FL(5, acc5) FL(6, acc6) FL(7, acc7) FL(8, acc8) FL(9, acc9)
  __syncthreads();
  float* dst = gacc + (bx & 3) * GSZ + (size_t)ch * 2560;
  for (int u2 = tid; u2 < 2560; u2 += 256)
    atomicAdd(&dst[u2], Pf[u2] + Pf[u2 + 2560] + Pf[u2 + 5120] + Pf[u2 + 7680]);
}

// ---------------------------------------------------------------------------
// Kernel 3: bordered 54x54 rank-8 blocked elimination (6 phases + 6x6 tail).
// One block per channel; first sums the 4 Gram replicas (10 KB) into LDS.
// M = [[pr_cov+aI, B^T],[B, la_cov+aI]]; pivots 27..53 = chol(appro+aI)^2.
// ---------------------------------------------------------------------------
#define MS 56   // row stride (doubles), even for 16-B alignment
__device__ inline double g54(const float* __restrict__ G, int R, int C) {
  int I = R >> 4, J = C >> 4;
  if (I > J) { int tt = R; R = C; C = tt; I = R >> 4; J = C >> 4; }
  int tile = 4 * I - ((I * (I - 1)) >> 1) + (J - I);
  int r = R & 15, c = C & 15;
  return (double)G[tile * 256 + (r & 3) * 64 + ((r >> 2) << 4) + c];
}

__device__ inline int tri_row(int u) {
  int a = (int)((sqrtf(8.0f * (float)u + 1.0f) - 1.0f) * 0.5f);
  while ((a + 1) * (a + 2) / 2 <= u) a++;
  while (a * (a + 1) / 2 > u) a--;
  return a;
}

__global__ __launch_bounds__(256) void stage2_kernel(
    const float* __restrict__ gacc, float* __restrict__ out) {
  __shared__ double M[54 * MS];
  __shared__ float gsf[2560];
  __shared__ double slv[27], spv[27], piv[54], lred[27];
  int ch = blockIdx.x, tid = threadIdx.x;
  const double Minv = 1.0 / (double)NVAL;
  const double alpha = 5e-4;

  // Sum the 4 replicas into LDS
  for (int u = tid; u < 2560; u += 256) {
    const float* p = gacc + (size_t)ch * 2560 + u;
    float s = 0.0f;
    #pragma unroll
    for (int r = 0; r < NREP; r++) s += p[r * GSZ];
    gsf[u] = s;
  }
  __syncthreads();
  const float* G = gsf;

  if (tid < 27) { slv[tid] = g54(G, tid, 54); spv[tid] = g54(G, 27 + tid, 54); }
  __syncthreads();
  // Build lower triangle of bordered matrix: 0..26 = pr dims, 27..53 = la
  for (int u = tid; u < 1485; u += 256) {
    int a = tri_row(u);
    int b = u - a * (a + 1) / 2;               // b <= a
    double v;
    if (a < 27) {                               // pr-pr
      v = g54(G, 27 + a, 27 + b) - spv[a] * spv[b] * Minv + ((a == b) ? alpha : 0.0);
    } else if (b >= 27) {                       // la-la
      int d = a - 27, e = b - 27;
      v = g54(G, d, e) - slv[d] * slv[e] * Minv + ((d == e) ? alpha : 0.0);
    } else {                                    // la row, pr col
      v = g54(G, a - 27, 27 + b) - slv[a - 27] * spv[b] * Minv;
    }
    M[a * MS + b] = v;
  }
  __syncthreads();

  #pragma unroll 1
  for (int phase = 0; phase < 6; phase++) {
    int k0 = phase * 8;
    // Load lower 8x8 pivot block (broadcast reads), factor LDL^T in regs
    double P[8][8];
    #pragma unroll
    for (int k = 0; k < 8; k++)
      #pragma unroll
      for (int j = 0; j <= k; j++)
        P[k][j] = M[(k0 + k) * MS + (k0 + j)];
    double idv[8];
    #pragma unroll
    for (int k = 0; k < 8; k++) {
      idv[k] = 1.0 / P[k][k];
      #pragma unroll
      for (int i = k + 1; i < 8; i++) {
        double l = P[i][k] * idv[k];
        #pragma unroll
        for (int j = k + 1; j <= i; j++)
          P[i][j] -= l * P[j][k];
      }
      #pragma unroll
      for (int i = k + 1; i < 8; i++) P[i][k] *= idv[k];
    }
    if (tid == 0) {
      #pragma unroll
      for (int k = 0; k < 8; k++) piv[k0 + k] = P[k][k];
    }
    int bstart = k0 + 8, n = 54 - bstart;
    int ncell = n * (n + 1) / 2;
    for (int u = tid; u < ncell; u += 256) {
      int ii = tri_row(u);
      int jj = u - ii * (ii + 1) / 2;
      int i = bstart + ii, j = bstart + jj;
      // 16-B aligned vector loads of the 8-double borders
      const double2* Ai = (const double2*)(M + i * MS + k0);
      const double2* Bj = (const double2*)(M + j * MS + k0);
      double2 a01 = Ai[0], a23 = Ai[1], a45 = Ai[2], a67 = Ai[3];
      double2 b01 = Bj[0], b23 = Bj[1], b45 = Bj[2], b67 = Bj[3];
      double av[8] = {a01.x, a01.y, a23.x, a23.y, a45.x, a45.y, a67.x, a67.y};
      double bv[8] = {b01.x, b01.y, b23.x, b23.y, b45.x, b45.y, b67.x, b67.y};
      #pragma unroll
      for (int k = 1; k < 8; k++) {
        #pragma unroll
        for (int m = 0; m < k; m++) {
          av[k] -= P[k][m] * av[m];
          bv[k] -= P[k][m] * bv[m];
        }
      }
      double acc = 0.0;
      #pragma unroll
      for (int k = 0; k < 8; k++) acc += av[k] * (bv[k] * idv[k]);
      M[i * MS + j] -= acc;
    }
    __syncthreads();
  }

  // Tail: 6x6 trailing block, pivots 48..53
  if (tid == 0) {
    double T[6][6];
    #pragma unroll
    for (int k = 0; k < 6; k++)
      #pragma unroll
      for (int j = 0; j <= k; j++)
        T[k][j] = M[(48 + k) * MS + (48 + j)];
    #pragma unroll
    for (int k = 0; k < 6; k++) {
      double dk = T[k][k];
      piv[48 + k] = dk;
      double id = 1.0 / dk;
      #pragma unroll
      for (int i = k + 1; i < 6; i++) {
        double l = T[i][k] * id;
        #pragma unroll
        for (int j = k + 1; j <= i; j++)
          T[i][j] -= l * T[j][k];
      }
    }
  }
  __syncthreads();

  if (tid < 27) lred[tid] = log(sqrt(piv[27 + tid]) + 1e-8);
  __syncthreads();
  if (tid == 0) {
    double s = 0.0;
    for (int i = 0; i < 27; i++) s += lred[i];
    atomicAdd(out, (float)(s / 54.0));
  }
}

// ---------------------------------------------------------------------------
extern "C" void kernel_launch(void* const* d_in, const int* in_sizes, int n_in,
                              void* d_out, int out_size, void* d_ws, size_t ws_size,
                              hipStream_t stream) {
  const float* logits = (const float*)d_in[0];
  const int* labels = (const int*)d_in[1];
  float* out = (float*)d_out;

  // ws layout: gacc fp32 x 4 replicas (320 KB, zeroed by pool) | shifted bf16
  float* gacc = (float*)d_ws;
  u16* shifted = (u16*)((char*)d_ws + 327680);

  pool_kernel<<<432, 256, 0, stream>>>(logits, labels, shifted, gacc, out);
  gram_kernel<<<512, 256, 0, stream>>>(shifted, gacc);
  stage2_kernel<<<NCH, 256, 0, stream>>>(gacc, out);
}